// Round 3
// baseline (513.954 us; speedup 1.0000x reference)
//
#include <hip/hip_runtime.h>
#include <math.h>

// CRF log-likelihood, B=512, S=512, T=128.
// fwd_kernel: 1 block (512 thr, 8 waves) per batch; thread (r=tid&3, c=tid>>2)
// owns E rows [32r,32r+32) x col c as float4 Efr[8] (32 VGPRs -- sized so the
// allocator provably keeps it; rounds 0-1 spilled 128-float fragments at
// VGPR_Count 80/96). p vector double-buffered in LDS, stored CHUNK-SWIZZLED
// (slot(g) = (g&~7)|((g+2*(g>>3))&7)) so the 4 r-groups read disjoint banks
// with static immediate offsets; Efr is loaded pre-permuted to match slots.
// Per step: 8 broadcast ds_read_b128 + 32 fmac; shfl_xor(1),(2) reduces over
// r; r==0 lanes do log/exp/score update and write next p; ONE barrier/step.
// sigma shift = col-0 score, 1-step delayed via sig_sh (any consistent shift
// is exact up to fp rounding; exp args bounded ~e^20).
// Numerator + denominator folded into the tail; reduce_kernel sums 512 partials.

#define T 128
#define SLEN 512
#define BATCH 512

__global__ __launch_bounds__(512, 4) void fwd_kernel(
    const float* __restrict__ em, const int* __restrict__ tags,
    const int* __restrict__ mask, const float* __restrict__ startT,
    const float* __restrict__ endT, const float* __restrict__ trans,
    float* __restrict__ ws)
{
    const int b   = blockIdx.x;
    const int tid = threadIdx.x;
    const int r   = tid & 3;          // row group: rows [32r, 32r+32)
    const int c   = tid >> 2;         // column 0..127
    const float* emb = em + (size_t)b * SLEN * T;
    const int*   mk  = mask + (size_t)b * SLEN;

    // Pre-permuted E fragment: Efr[i] pairs with LDS slot-chunk (8r + i).
    float4 Efr[8];
#pragma unroll
    for (int i = 0; i < 8; ++i) {
        const int q    = (i + 16 - 2 * r) & 7;   // local chunk stored in slot 8r+i
        const int row0 = 32 * r + 4 * q;
        Efr[i].x = __expf(trans[(row0 + 0) * T + c]);
        Efr[i].y = __expf(trans[(row0 + 1) * T + c]);
        Efr[i].z = __expf(trans[(row0 + 2) * T + c]);
        Efr[i].w = __expf(trans[(row0 + 3) * T + c]);
    }

    __shared__ __align__(16) float p_sh[2][T];
    __shared__ float sig_sh[2];
    __shared__ float redm[8], reds[8], redn[8];
    __shared__ int   redc[8];

    // Reader bases: thread reads slot-chunks 8r+0 .. 8r+7 (imm offsets i*16).
    const char* rb0 = (const char*)&p_sh[0][0] + r * 128;
    const char* rb1 = (const char*)&p_sh[1][0] + r * 128;
    // Writer offset (r==0 lanes): element c -> slot(c>>2), word lane (c&3).
    const int g      = c >> 2;
    const int slot   = (g & ~7) | ((g + 2 * (g >> 3)) & 7);
    const int wr_off = slot * 16 + (c & 3) * 4;
    char* wb0 = (char*)&p_sh[0][0] + wr_off;
    char* wb1 = (char*)&p_sh[1][0] + wr_off;

    // alpha_0 (scores live in r==0 lanes)
    float score = 0.f;
    if (r == 0) {
        score = startT[c] + emb[c];
        *(float*)wb1 = __expf(score);        // shift 0 for step 1
        if (tid == 0) sig_sh[1] = score;     // shift for step 2
    }
    float sigma = 0.f;

    // 4-deep emission/mask prefetch
    float emv[4], emn[4];
    int   mkv[4], mkn[4];
#pragma unroll
    for (int k = 0; k < 4; ++k) { emv[k] = emb[(1 + k) * T + c]; mkv[k] = mk[1 + k]; }
    __syncthreads();

    for (int s0 = 1; s0 < SLEN; s0 += 4) {
#pragma unroll
        for (int k = 0; k < 4; ++k) {
            int ss = s0 + 4 + k; ss = (ss < SLEN) ? ss : (SLEN - 1);
            emn[k] = emb[ss * T + c];
            mkn[k] = mk[ss];
        }
#pragma unroll
        for (int k = 0; k < 4; ++k) {
            const int s = s0 + k;
            if (s < SLEN) {                        // uniform guard (511 steps)
                const int cur = (1 + k) & 1;       // == s&1 (s0 odd): compile-time
                const char* rb = cur ? rb1 : rb0;
                float a0 = 0.f, a1 = 0.f, a2 = 0.f, a3 = 0.f;
#pragma unroll
                for (int i = 0; i < 8; ++i) {
                    const float4 pv = *(const float4*)(rb + i * 16);
                    a0 = fmaf(pv.x, Efr[i].x, a0);
                    a1 = fmaf(pv.y, Efr[i].y, a1);
                    a2 = fmaf(pv.z, Efr[i].z, a2);
                    a3 = fmaf(pv.w, Efr[i].w, a3);
                }
                float t = (a0 + a1) + (a2 + a3);
                t += __shfl_xor(t, 1);             // reduce over r (tid bits 0,1)
                t += __shfl_xor(t, 2);
                const float sig_next = sig_sh[cur];
                if (r == 0) {
                    const float n = sigma + __logf(t) + emv[k];
                    score = (mkv[k] > 0) ? n : score;
                    const float pp = __expf(score - sig_next);
                    *(float*)(cur ? wb0 : wb1) = pp;       // buffer cur^1
                    if (tid == 0) sig_sh[cur ^ 1] = score;
                }
                sigma = sig_next;
                __syncthreads();
            }
        }
#pragma unroll
        for (int k = 0; k < 4; ++k) { emv[k] = emn[k]; mkv[k] = mkn[k]; }
    }

    // ---- denominator: logsumexp_c(score_c + endT_c) ----
    const int wid = tid >> 6, lane = tid & 63;
    float v = (r == 0) ? (score + endT[c]) : -INFINITY;
    float m = v;
#pragma unroll
    for (int off = 32; off; off >>= 1) m = fmaxf(m, __shfl_xor(m, off));
    if (lane == 0) redm[wid] = m;
    __syncthreads();
    float M = redm[0];
#pragma unroll
    for (int i = 1; i < 8; ++i) M = fmaxf(M, redm[i]);
    float sm = (r == 0) ? __expf(v - M) : 0.f;
#pragma unroll
    for (int off = 32; off; off >>= 1) sm += __shfl_xor(sm, off);
    if (lane == 0) reds[wid] = sm;

    // ---- numerator: one sequence step per thread ----
    const int* tg = tags + (size_t)b * SLEN;
    const int mm = mk[tid];
    int   cnt = (mm != 0);
    float nv  = 0.f;
    if (tid >= 1 && mm > 0)
        nv = trans[tg[tid - 1] * T + tg[tid]] + emb[tid * T + tg[tid]];
#pragma unroll
    for (int off = 32; off; off >>= 1) {
        nv  += __shfl_xor(nv, off);
        cnt += __shfl_xor(cnt, off);
    }
    if (lane == 0) { redn[wid] = nv; redc[wid] = cnt; }
    __syncthreads();
    if (tid == 0) {
        float ssum = 0.f, nsum = 0.f; int seqlen = 0;
#pragma unroll
        for (int i = 0; i < 8; ++i) { ssum += reds[i]; nsum += redn[i]; seqlen += redc[i]; }
        const float denom = M + __logf(ssum);
        const int t0 = tg[0], tl = tg[seqlen - 1];
        ws[b] = (startT[t0] + emb[t0] + endT[tl] + nsum) - denom;
    }
}

__global__ __launch_bounds__(256) void reduce_kernel(
    const float* __restrict__ ws, float* __restrict__ out)
{
    const int t = threadIdx.x;          // one block of 256
    float local = 0.f;
    for (int i = t; i < BATCH; i += 256) local += ws[i];
    __shared__ float rf[256];
    rf[t] = local;
    __syncthreads();
    for (int off = 128; off > 0; off >>= 1) {
        if (t < off) rf[t] += rf[t + off];
        __syncthreads();
    }
    if (t == 0) out[0] = rf[0];
}

extern "C" void kernel_launch(void* const* d_in, const int* in_sizes, int n_in,
                              void* d_out, int out_size, void* d_ws, size_t ws_size,
                              hipStream_t stream)
{
    const float* emissions = (const float*)d_in[0];
    const int*   tags      = (const int*)d_in[1];
    const int*   mask      = (const int*)d_in[2];
    const float* startT    = (const float*)d_in[3];
    const float* endT      = (const float*)d_in[4];
    const float* trans     = (const float*)d_in[5];
    float* out = (float*)d_out;
    float* ws  = (float*)d_ws;          // BATCH floats of per-batch partials

    fwd_kernel<<<BATCH, 512, 0, stream>>>(emissions, tags, mask, startT, endT, trans, ws);
    reduce_kernel<<<1, 256, 0, stream>>>(ws, out);
}

// Round 4
// 417.529 us; speedup vs baseline: 1.2309x; 1.2309x over previous
//
#include <hip/hip_runtime.h>
#include <math.h>

// CRF log-likelihood, B=512, S=512, T=128.
// fwd_kernel: 1 block (512 thr, 8 waves) per batch; thread (r=tid&3, c=tid>>2)
// owns E rows [32r,32r+32) x col c as float4 Efr[8] (32 VGPRs; bigger
// fragments spilled in rounds 1-2 at VGPR_Count 80/96).
// p double-buffered in LDS, PLAIN layout (element c at float offset c).
// Bank-conflict fix (round 3 had 6.7e7 conflict cycles): each r-group reads
// its 8 chunks in ROTATED ORDER idx[i] = 8r + ((i+2r)&7), so instruction i
// touches banks 4*((i+2r)&7) -- disjoint across r. idx[] precomputed in
// registers; Efr[i] holds rows 4*idx[i]..4*idx[i]+3 to match. Round 3's bug:
// it permuted p STORAGE but kept read addresses r*128+i*16, leaving all four
// r-groups on banks 4i every instruction.
// Per step: 8 broadcast ds_read_b128 + 32 fmac; shfl_xor(1),(2) reduce over r;
// r==0 lanes do log/exp/score update + write next p; ONE barrier/step.
// sigma shift = col-0 score, 1-step delayed via sig_sh (any consistent shift
// is mathematically exact; exp args bounded ~e^20, fp32-safe).
// Numerator + denominator folded into tail; reduce_kernel sums 512 partials.

#define T 128
#define SLEN 512
#define BATCH 512

__global__ __launch_bounds__(512, 4) void fwd_kernel(
    const float* __restrict__ em, const int* __restrict__ tags,
    const int* __restrict__ mask, const float* __restrict__ startT,
    const float* __restrict__ endT, const float* __restrict__ trans,
    float* __restrict__ ws)
{
    const int b   = blockIdx.x;
    const int tid = threadIdx.x;
    const int r   = tid & 3;          // row group: rows [32r, 32r+32)
    const int c   = tid >> 2;         // column 0..127
    const float* emb = em + (size_t)b * SLEN * T;
    const int*   mk  = mask + (size_t)b * SLEN;

    // Per-thread read schedule (registers, reused all steps) + matching E frag.
    int idx[8];
#pragma unroll
    for (int i = 0; i < 8; ++i) idx[i] = 8 * r + ((i + 2 * r) & 7);

    float4 Efr[8];
#pragma unroll
    for (int i = 0; i < 8; ++i) {
        const int row0 = 4 * idx[i];
        Efr[i].x = __expf(trans[(row0 + 0) * T + c]);
        Efr[i].y = __expf(trans[(row0 + 1) * T + c]);
        Efr[i].z = __expf(trans[(row0 + 2) * T + c]);
        Efr[i].w = __expf(trans[(row0 + 3) * T + c]);
    }

    __shared__ __align__(16) float4 psh4[2][T / 4];   // plain: elem c at word c
    __shared__ float sig_sh[2];
    __shared__ float redm[8], reds[8], redn[8];
    __shared__ int   redc[8];

    // alpha_0 (scores live in r==0 lanes)
    float score = 0.f;
    if (r == 0) {
        score = startT[c] + emb[c];
        ((float*)&psh4[1][0])[c] = __expf(score);   // shift 0 for step 1
        if (tid == 0) sig_sh[1] = score;            // shift for step 2
    }
    float sigma = 0.f;

    // 4-deep emission/mask prefetch
    float emv[4], emn[4];
    int   mkv[4], mkn[4];
#pragma unroll
    for (int k = 0; k < 4; ++k) { emv[k] = emb[(1 + k) * T + c]; mkv[k] = mk[1 + k]; }
    __syncthreads();

    for (int s0 = 1; s0 < SLEN; s0 += 4) {
#pragma unroll
        for (int k = 0; k < 4; ++k) {
            int ss = s0 + 4 + k; ss = (ss < SLEN) ? ss : (SLEN - 1);
            emn[k] = emb[ss * T + c];
            mkn[k] = mk[ss];
        }
#pragma unroll
        for (int k = 0; k < 4; ++k) {
            const int s = s0 + k;
            if (s < SLEN) {                        // uniform guard (511 steps)
                const int cur = (1 + k) & 1;       // == s&1 (s0 odd): compile-time
                float a0 = 0.f, a1 = 0.f, a2 = 0.f, a3 = 0.f;
#pragma unroll
                for (int i = 0; i < 8; ++i) {
                    const float4 pv = psh4[cur][idx[i]];   // conflict-free rotated
                    a0 = fmaf(pv.x, Efr[i].x, a0);
                    a1 = fmaf(pv.y, Efr[i].y, a1);
                    a2 = fmaf(pv.z, Efr[i].z, a2);
                    a3 = fmaf(pv.w, Efr[i].w, a3);
                }
                float t = (a0 + a1) + (a2 + a3);
                t += __shfl_xor(t, 1);             // reduce over r (tid bits 0,1)
                t += __shfl_xor(t, 2);
                const float sig_next = sig_sh[cur];
                if (r == 0) {
                    const float n = sigma + __logf(t) + emv[k];
                    score = (mkv[k] > 0) ? n : score;
                    const float pp = __expf(score - sig_next);
                    ((float*)&psh4[cur ^ 1][0])[c] = pp;
                    if (tid == 0) sig_sh[cur ^ 1] = score;
                }
                sigma = sig_next;
                __syncthreads();
            }
        }
#pragma unroll
        for (int k = 0; k < 4; ++k) { emv[k] = emn[k]; mkv[k] = mkn[k]; }
    }

    // ---- denominator: logsumexp_c(score_c + endT_c) ----
    const int wid = tid >> 6, lane = tid & 63;
    float v = (r == 0) ? (score + endT[c]) : -INFINITY;
    float m = v;
#pragma unroll
    for (int off = 32; off; off >>= 1) m = fmaxf(m, __shfl_xor(m, off));
    if (lane == 0) redm[wid] = m;
    __syncthreads();
    float M = redm[0];
#pragma unroll
    for (int i = 1; i < 8; ++i) M = fmaxf(M, redm[i]);
    float sm = (r == 0) ? __expf(v - M) : 0.f;
#pragma unroll
    for (int off = 32; off; off >>= 1) sm += __shfl_xor(sm, off);
    if (lane == 0) reds[wid] = sm;

    // ---- numerator: one sequence step per thread ----
    const int* tg = tags + (size_t)b * SLEN;
    const int mm = mk[tid];
    int   cnt = (mm != 0);
    float nv  = 0.f;
    if (tid >= 1 && mm > 0)
        nv = trans[tg[tid - 1] * T + tg[tid]] + emb[tid * T + tg[tid]];
#pragma unroll
    for (int off = 32; off; off >>= 1) {
        nv  += __shfl_xor(nv, off);
        cnt += __shfl_xor(cnt, off);
    }
    if (lane == 0) { redn[wid] = nv; redc[wid] = cnt; }
    __syncthreads();
    if (tid == 0) {
        float ssum = 0.f, nsum = 0.f; int seqlen = 0;
#pragma unroll
        for (int i = 0; i < 8; ++i) { ssum += reds[i]; nsum += redn[i]; seqlen += redc[i]; }
        const float denom = M + __logf(ssum);
        const int t0 = tg[0], tl = tg[seqlen - 1];
        ws[b] = (startT[t0] + emb[t0] + endT[tl] + nsum) - denom;
    }
}

__global__ __launch_bounds__(256) void reduce_kernel(
    const float* __restrict__ ws, float* __restrict__ out)
{
    const int t = threadIdx.x;          // one block of 256
    float local = 0.f;
    for (int i = t; i < BATCH; i += 256) local += ws[i];
    __shared__ float rf[256];
    rf[t] = local;
    __syncthreads();
    for (int off = 128; off > 0; off >>= 1) {
        if (t < off) rf[t] += rf[t + off];
        __syncthreads();
    }
    if (t == 0) out[0] = rf[0];
}

extern "C" void kernel_launch(void* const* d_in, const int* in_sizes, int n_in,
                              void* d_out, int out_size, void* d_ws, size_t ws_size,
                              hipStream_t stream)
{
    const float* emissions = (const float*)d_in[0];
    const int*   tags      = (const int*)d_in[1];
    const int*   mask      = (const int*)d_in[2];
    const float* startT    = (const float*)d_in[3];
    const float* endT      = (const float*)d_in[4];
    const float* trans     = (const float*)d_in[5];
    float* out = (float*)d_out;
    float* ws  = (float*)d_ws;          // BATCH floats of per-batch partials

    fwd_kernel<<<BATCH, 512, 0, stream>>>(emissions, tags, mask, startT, endT, trans, ws);
    reduce_kernel<<<1, 256, 0, stream>>>(ws, out);
}